// Round 1
// baseline (575.364 us; speedup 1.0000x reference)
//
#include <hip/hip_runtime.h>

typedef __attribute__((ext_vector_type(8))) short bf16x8;
typedef __attribute__((ext_vector_type(4))) float f32x4;
typedef unsigned short u16;
typedef unsigned int u32;

#define T_SEQ 2048
#define C_DIM 1024
#define NH 16
#define HD 64
#define BATCH 2

__device__ __forceinline__ u16 f2bf(float f) {
    union { float f; u32 u; } v; v.f = f;
    u32 u = v.u;
    u32 r = (u + 0x7FFFu + ((u >> 16) & 1u)) >> 16;
    return (u16)r;
}

// ---------------------------------------------------------------------------
// Transpose 4 weight matrices [C,C] f32 -> [C,C] bf16 (WT[n][k] = W[k][n])
// ---------------------------------------------------------------------------
__global__ __launch_bounds__(256) void transpose_to_bf16(
    const float* __restrict__ W0, const float* __restrict__ W1,
    const float* __restrict__ W2, const float* __restrict__ W3,
    u16* __restrict__ O0, u16* __restrict__ O1,
    u16* __restrict__ O2, u16* __restrict__ O3)
{
    __shared__ float tile[32][33];
    const float* W = blockIdx.z == 0 ? W0 : blockIdx.z == 1 ? W1 : blockIdx.z == 2 ? W2 : W3;
    u16* O = blockIdx.z == 0 ? O0 : blockIdx.z == 1 ? O1 : blockIdx.z == 2 ? O2 : O3;
    const int tx = threadIdx.x, ty = threadIdx.y;
    const int bx = blockIdx.x * 32, by = blockIdx.y * 32;
#pragma unroll
    for (int i = 0; i < 4; ++i)
        tile[ty + i * 8][tx] = W[(size_t)(by + ty + i * 8) * C_DIM + bx + tx];
    __syncthreads();
#pragma unroll
    for (int i = 0; i < 4; ++i)
        O[(size_t)(bx + ty + i * 8) * C_DIM + by + tx] = f2bf(tile[tx][ty + i * 8]);
}

// ---------------------------------------------------------------------------
// GEMM: Y[M,N] = X[M,K] @ W[K,N] + bias, with WT[N,K] (pre-transposed bf16).
// X is f32 (XF32) or bf16. Y is f32 (OUTF32) or bf16.
// 128x128 tile, BK=32, 256 threads (4 waves, each 64x64 via 4x4 16x16 frags).
// ---------------------------------------------------------------------------
template<bool XF32, bool OUTF32>
__global__ __launch_bounds__(256) void gemm_bt(
    const void* __restrict__ Xv, const u16* __restrict__ WT,
    const float* __restrict__ bias, void* __restrict__ Yv,
    int M, int N, int K)
{
    __shared__ u16 As[128 * 32];
    __shared__ u16 Bs[128 * 32];
    const int tid = threadIdx.x;
    const int w = tid >> 6, l = tid & 63;
    const int lr = l & 15, lg = l >> 4;
    const int m0 = blockIdx.y * 128, n0 = blockIdx.x * 128;
    const int wr = (w >> 1) * 64, wc = (w & 1) * 64;
    f32x4 acc[4][4] = {};

    for (int k0 = 0; k0 < K; k0 += 32) {
        __syncthreads();
#pragma unroll
        for (int r = 0; r < 2; ++r) {
            const int idx = r * 256 + tid;      // 0..511
            const int row = idx >> 2, cg = idx & 3;
            if (XF32) {
                const float* g = (const float*)Xv + (size_t)(m0 + row) * K + k0 + cg * 8;
                float4 a0 = *(const float4*)g;
                float4 a1 = *(const float4*)(g + 4);
                union { u16 h[8]; uint4 q; } pk;
                pk.h[0] = f2bf(a0.x); pk.h[1] = f2bf(a0.y);
                pk.h[2] = f2bf(a0.z); pk.h[3] = f2bf(a0.w);
                pk.h[4] = f2bf(a1.x); pk.h[5] = f2bf(a1.y);
                pk.h[6] = f2bf(a1.z); pk.h[7] = f2bf(a1.w);
                *(uint4*)&As[row * 32 + cg * 8] = pk.q;
            } else {
                const u16* g = (const u16*)Xv + (size_t)(m0 + row) * K + k0 + cg * 8;
                *(uint4*)&As[row * 32 + cg * 8] = *(const uint4*)g;
            }
            const u16* gb = WT + (size_t)(n0 + row) * K + k0 + cg * 8;
            *(uint4*)&Bs[row * 32 + cg * 8] = *(const uint4*)gb;
        }
        __syncthreads();
        bf16x8 af[4], bfr[4];
#pragma unroll
        for (int i = 0; i < 4; ++i)
            af[i] = *(const bf16x8*)&As[(wr + i * 16 + lr) * 32 + lg * 8];
#pragma unroll
        for (int j = 0; j < 4; ++j)
            bfr[j] = *(const bf16x8*)&Bs[(wc + j * 16 + lr) * 32 + lg * 8];
#pragma unroll
        for (int i = 0; i < 4; ++i)
#pragma unroll
            for (int j = 0; j < 4; ++j)
                acc[i][j] = __builtin_amdgcn_mfma_f32_16x16x32_bf16(af[i], bfr[j], acc[i][j], 0, 0, 0);
    }

#pragma unroll
    for (int i = 0; i < 4; ++i) {
        const int rowb = m0 + wr + i * 16 + lg * 4;
#pragma unroll
        for (int j = 0; j < 4; ++j) {
            const int col = n0 + wc + j * 16 + lr;
            const float bv = bias[col];
#pragma unroll
            for (int r = 0; r < 4; ++r) {
                const float v = acc[i][j][r] + bv;
                if (OUTF32)
                    ((float*)Yv)[(size_t)(rowb + r) * N + col] = v;
                else
                    ((u16*)Yv)[(size_t)(rowb + r) * N + col] = f2bf(v);
            }
        }
    }
}

// ---------------------------------------------------------------------------
// Causal attention, 2-pass flash style.
// Block = (b, h, 64 q-rows); 4 waves x 16 q-rows each.
// Pass 1: running (m, l) per row. Pass 2: recompute S, write normalized P
// (f32) to d_out attn region (zeros above diagonal), PV-accumulate ctx.
// ---------------------------------------------------------------------------
__global__ __launch_bounds__(256) void attn_kernel(
    const u16* __restrict__ qp, const u16* __restrict__ kp,
    const u16* __restrict__ vp, u16* __restrict__ ctx,
    float* __restrict__ attn)
{
    __shared__ u16 plds[4][16][40];   // per-wave P tile, padded stride 40 (80B)
    const int l = threadIdx.x & 63, w = threadIdx.x >> 6;
    const int lr = l & 15, lg = l >> 4;
    const int b = blockIdx.z, h = blockIdx.y;
    const int q0 = blockIdx.x * 64 + w * 16;

    const size_t bh_off = (size_t)b * T_SEQ * C_DIM + h * HD;
    const u16* qb = qp + bh_off;
    const u16* kb = kp + bh_off;
    const u16* vb = vp + bh_off;
    float* ab = attn + (size_t)(b * NH + h) * T_SEQ * T_SEQ;

    // Q fragments (rows q0+lr, d = {0..31}, {32..63})
    const bf16x8 aq0 = *(const bf16x8*)(qb + (size_t)(q0 + lr) * C_DIM + lg * 8);
    const bf16x8 aq1 = *(const bf16x8*)(qb + (size_t)(q0 + lr) * C_DIM + 32 + lg * 8);

    float m[4], lsum[4];
#pragma unroll
    for (int r = 0; r < 4; ++r) { m[r] = -__builtin_inff(); lsum[r] = 0.f; }

    const int kv_end = q0 + 16;  // exclusive bound on valid kv for this strip

    // ---- pass 1: row max + sumexp ----
    for (int kv0 = 0; kv0 < kv_end; kv0 += 32) {
        f32x4 s[2] = {};
#pragma unroll
        for (int t = 0; t < 2; ++t) {
            const u16* kr = kb + (size_t)(kv0 + t * 16 + lr) * C_DIM;
            bf16x8 b0 = *(const bf16x8*)(kr + lg * 8);
            bf16x8 b1 = *(const bf16x8*)(kr + 32 + lg * 8);
            s[t] = __builtin_amdgcn_mfma_f32_16x16x32_bf16(aq0, b0, s[t], 0, 0, 0);
            s[t] = __builtin_amdgcn_mfma_f32_16x16x32_bf16(aq1, b1, s[t], 0, 0, 0);
        }
#pragma unroll
        for (int r = 0; r < 4; ++r) {
            const int row = q0 + lg * 4 + r;
            float s0 = s[0][r] * 0.125f; if (kv0 + lr > row)      s0 = -__builtin_inff();
            float s1 = s[1][r] * 0.125f; if (kv0 + 16 + lr > row) s1 = -__builtin_inff();
            float mt = fmaxf(s0, s1);
#pragma unroll
            for (int d = 1; d < 16; d <<= 1) mt = fmaxf(mt, __shfl_xor(mt, d));
            const float mn = fmaxf(m[r], mt);
            float e = __expf(s0 - mn) + __expf(s1 - mn);
#pragma unroll
            for (int d = 1; d < 16; d <<= 1) e += __shfl_xor(e, d);
            lsum[r] = lsum[r] * __expf(m[r] - mn) + e;
            m[r] = mn;
        }
    }

    float rl[4];
#pragma unroll
    for (int r = 0; r < 4; ++r) rl[r] = 1.f / lsum[r];

    f32x4 cacc[4] = {};

    // ---- pass 2: write P, accumulate PV ----
    for (int kv0 = 0; kv0 < T_SEQ; kv0 += 32) {
        if (kv0 >= kv_end) {
            // strictly above diagonal for all 16 rows: exact zeros
            const float4 z = make_float4(0.f, 0.f, 0.f, 0.f);
#pragma unroll
            for (int i = 0; i < 2; ++i) {
                const int idx = i * 64 + l;
                const int row = q0 + (idx >> 3);
                const int c4 = (idx & 7) * 4;
                *(float4*)(ab + (size_t)row * T_SEQ + kv0 + c4) = z;
            }
            continue;
        }
        f32x4 s[2] = {};
#pragma unroll
        for (int t = 0; t < 2; ++t) {
            const u16* kr = kb + (size_t)(kv0 + t * 16 + lr) * C_DIM;
            bf16x8 b0 = *(const bf16x8*)(kr + lg * 8);
            bf16x8 b1 = *(const bf16x8*)(kr + 32 + lg * 8);
            s[t] = __builtin_amdgcn_mfma_f32_16x16x32_bf16(aq0, b0, s[t], 0, 0, 0);
            s[t] = __builtin_amdgcn_mfma_f32_16x16x32_bf16(aq1, b1, s[t], 0, 0, 0);
        }
#pragma unroll
        for (int r = 0; r < 4; ++r) {
            const int row = q0 + lg * 4 + r;
            float s0 = s[0][r] * 0.125f; if (kv0 + lr > row)      s0 = -__builtin_inff();
            float s1 = s[1][r] * 0.125f; if (kv0 + 16 + lr > row) s1 = -__builtin_inff();
            const float p0 = __expf(s0 - m[r]) * rl[r];
            const float p1 = __expf(s1 - m[r]) * rl[r];
            float* arow = ab + (size_t)row * T_SEQ + kv0;
            arow[lr] = p0;
            arow[16 + lr] = p1;
            plds[w][lg * 4 + r][lr] = f2bf(p0);
            plds[w][lg * 4 + r][16 + lr] = f2bf(p1);
        }
        asm volatile("s_waitcnt lgkmcnt(0)" ::: "memory");
        // A-frag for PV: rows q0+lr, k = kv-local 8*lg+j
        const bf16x8 pa = *(const bf16x8*)&plds[w][lr][lg * 8];
#pragma unroll
        for (int dt = 0; dt < 4; ++dt) {
            union { u16 hsrc[8]; bf16x8 v; } bvv;
#pragma unroll
            for (int j = 0; j < 8; ++j)
                bvv.hsrc[j] = vb[(size_t)(kv0 + lg * 8 + j) * C_DIM + dt * 16 + lr];
            cacc[dt] = __builtin_amdgcn_mfma_f32_16x16x32_bf16(pa, bvv.v, cacc[dt], 0, 0, 0);
        }
    }

    u16* cb = ctx + bh_off;
#pragma unroll
    for (int dt = 0; dt < 4; ++dt)
#pragma unroll
        for (int r = 0; r < 4; ++r)
            cb[(size_t)(q0 + lg * 4 + r) * C_DIM + dt * 16 + lr] = f2bf(cacc[dt][r]);
}

// ---------------------------------------------------------------------------
extern "C" void kernel_launch(void* const* d_in, const int* in_sizes, int n_in,
                              void* d_out, int out_size, void* d_ws, size_t ws_size,
                              hipStream_t stream)
{
    const float* q  = (const float*)d_in[0];
    const float* k  = (const float*)d_in[1];
    const float* Wq = (const float*)d_in[2];
    const float* bq = (const float*)d_in[3];
    const float* Wk = (const float*)d_in[4];
    const float* bk = (const float*)d_in[5];
    const float* Wv = (const float*)d_in[6];
    const float* bv = (const float*)d_in[7];
    const float* Wo = (const float*)d_in[8];
    const float* bo = (const float*)d_in[9];
    (void)in_sizes; (void)n_in; (void)out_size; (void)ws_size;

    float* out = (float*)d_out;
    float* attn = out + (size_t)BATCH * T_SEQ * C_DIM;

    const size_t MC = (size_t)BATCH * T_SEQ * C_DIM;   // 4,194,304 elems
    u16* qp  = (u16*)d_ws;
    u16* kp  = qp + MC;
    u16* vp  = kp + MC;
    u16* ctx = vp + MC;
    u16* WqT = ctx + MC;
    u16* WkT = WqT + (size_t)C_DIM * C_DIM;
    u16* WvT = WkT + (size_t)C_DIM * C_DIM;
    u16* WoT = WvT + (size_t)C_DIM * C_DIM;

    transpose_to_bf16<<<dim3(32, 32, 4), dim3(32, 8), 0, stream>>>(
        Wq, Wk, Wv, Wo, WqT, WkT, WvT, WoT);

    const int M = BATCH * T_SEQ;
    dim3 gg(C_DIM / 128, M / 128);
    gemm_bt<true,  false><<<gg, 256, 0, stream>>>(q,  WqT, bq, qp, M, C_DIM, C_DIM);
    gemm_bt<true,  false><<<gg, 256, 0, stream>>>(k,  WkT, bk, kp, M, C_DIM, C_DIM);
    gemm_bt<false, false><<<gg, 256, 0, stream>>>(kp, WvT, bv, vp, M, C_DIM, C_DIM);

    attn_kernel<<<dim3(T_SEQ / 64, NH, BATCH), 256, 0, stream>>>(qp, kp, vp, ctx, attn);

    gemm_bt<false, true><<<gg, 256, 0, stream>>>(ctx, WoT, bo, out, M, C_DIM, C_DIM);
}

// Round 2
// 517.160 us; speedup vs baseline: 1.1125x; 1.1125x over previous
//
#include <hip/hip_runtime.h>

typedef __attribute__((ext_vector_type(8))) short bf16x8;
typedef __attribute__((ext_vector_type(4))) float f32x4;
typedef unsigned short u16;
typedef unsigned int u32;

#define T_SEQ 2048
#define C_DIM 1024
#define NH 16
#define HD 64
#define BATCH 2

__device__ __forceinline__ u16 f2bf(float f) {
    union { float f; u32 u; } v; v.f = f;
    u32 u = v.u;
    u32 r = (u + 0x7FFFu + ((u >> 16) & 1u)) >> 16;
    return (u16)r;
}

// exp2 via native v_exp_f32
__device__ __forceinline__ float fexp2(float x) { return __builtin_amdgcn_exp2f(x); }

// ---------------------------------------------------------------------------
// Transpose 4 weight matrices [C,C] f32 -> [C,C] bf16 (WT[n][k] = W[k][n])
// ---------------------------------------------------------------------------
__global__ __launch_bounds__(256) void transpose_to_bf16(
    const float* __restrict__ W0, const float* __restrict__ W1,
    const float* __restrict__ W2, const float* __restrict__ W3,
    u16* __restrict__ O0, u16* __restrict__ O1,
    u16* __restrict__ O2, u16* __restrict__ O3)
{
    __shared__ float tile[32][33];
    const float* W = blockIdx.z == 0 ? W0 : blockIdx.z == 1 ? W1 : blockIdx.z == 2 ? W2 : W3;
    u16* O = blockIdx.z == 0 ? O0 : blockIdx.z == 1 ? O1 : blockIdx.z == 2 ? O2 : O3;
    const int tx = threadIdx.x, ty = threadIdx.y;
    const int bx = blockIdx.x * 32, by = blockIdx.y * 32;
#pragma unroll
    for (int i = 0; i < 4; ++i)
        tile[ty + i * 8][tx] = W[(size_t)(by + ty + i * 8) * C_DIM + bx + tx];
    __syncthreads();
#pragma unroll
    for (int i = 0; i < 4; ++i)
        O[(size_t)(bx + ty + i * 8) * C_DIM + by + tx] = f2bf(tile[tx][ty + i * 8]);
}

// ---------------------------------------------------------------------------
// GEMM: Y[M,N] = X[M,K] @ W[K,N] + bias, with WT[N,K] (pre-transposed bf16).
// OMODE: 0 = bf16 row-major, 1 = f32 row-major,
//        2 = bf16 transposed per-head: Y[b][h][d][t]  (for V^T)
// ---------------------------------------------------------------------------
template<bool XF32, int OMODE>
__global__ __launch_bounds__(256) void gemm_bt(
    const void* __restrict__ Xv, const u16* __restrict__ WT,
    const float* __restrict__ bias, void* __restrict__ Yv,
    int M, int N, int K)
{
    __shared__ u16 As[128 * 32];
    __shared__ u16 Bs[128 * 32];
    const int tid = threadIdx.x;
    const int w = tid >> 6, l = tid & 63;
    const int lr = l & 15, lg = l >> 4;
    const int m0 = blockIdx.y * 128, n0 = blockIdx.x * 128;
    const int wr = (w >> 1) * 64, wc = (w & 1) * 64;
    f32x4 acc[4][4] = {};

    for (int k0 = 0; k0 < K; k0 += 32) {
        __syncthreads();
#pragma unroll
        for (int r = 0; r < 2; ++r) {
            const int idx = r * 256 + tid;      // 0..511
            const int row = idx >> 2, cg = idx & 3;
            if (XF32) {
                const float* g = (const float*)Xv + (size_t)(m0 + row) * K + k0 + cg * 8;
                float4 a0 = *(const float4*)g;
                float4 a1 = *(const float4*)(g + 4);
                union { u16 h[8]; uint4 q; } pk;
                pk.h[0] = f2bf(a0.x); pk.h[1] = f2bf(a0.y);
                pk.h[2] = f2bf(a0.z); pk.h[3] = f2bf(a0.w);
                pk.h[4] = f2bf(a1.x); pk.h[5] = f2bf(a1.y);
                pk.h[6] = f2bf(a1.z); pk.h[7] = f2bf(a1.w);
                *(uint4*)&As[row * 32 + cg * 8] = pk.q;
            } else {
                const u16* g = (const u16*)Xv + (size_t)(m0 + row) * K + k0 + cg * 8;
                *(uint4*)&As[row * 32 + cg * 8] = *(const uint4*)g;
            }
            const u16* gb = WT + (size_t)(n0 + row) * K + k0 + cg * 8;
            *(uint4*)&Bs[row * 32 + cg * 8] = *(const uint4*)gb;
        }
        __syncthreads();
        bf16x8 af[4], bfr[4];
#pragma unroll
        for (int i = 0; i < 4; ++i)
            af[i] = *(const bf16x8*)&As[(wr + i * 16 + lr) * 32 + lg * 8];
#pragma unroll
        for (int j = 0; j < 4; ++j)
            bfr[j] = *(const bf16x8*)&Bs[(wc + j * 16 + lr) * 32 + lg * 8];
#pragma unroll
        for (int i = 0; i < 4; ++i)
#pragma unroll
            for (int j = 0; j < 4; ++j)
                acc[i][j] = __builtin_amdgcn_mfma_f32_16x16x32_bf16(af[i], bfr[j], acc[i][j], 0, 0, 0);
    }

#pragma unroll
    for (int i = 0; i < 4; ++i) {
        const int rowb = m0 + wr + i * 16 + lg * 4;
#pragma unroll
        for (int j = 0; j < 4; ++j) {
            const int col = n0 + wc + j * 16 + lr;
            const float bv = bias[col];
            if (OMODE == 2) {
                // V^T: vt[((b*NH + h)*HD + d)*T + t], b=row>>11, t=row&2047,
                // h=col>>6, d=col&63; r gives 4 consecutive t -> 8B store
                union { u16 h[4]; uint2 q; } pk;
#pragma unroll
                for (int r = 0; r < 4; ++r) pk.h[r] = f2bf(acc[i][j][r] + bv);
                const int bb = rowb >> 11, tt = rowb & 2047;
                const int hh = col >> 6, dd = col & 63;
                u16* dst = (u16*)Yv + ((size_t)((bb * NH + hh) * HD + dd)) * T_SEQ + tt;
                *(uint2*)dst = pk.q;
            } else {
#pragma unroll
                for (int r = 0; r < 4; ++r) {
                    const float v = acc[i][j][r] + bv;
                    if (OMODE == 1)
                        ((float*)Yv)[(size_t)(rowb + r) * N + col] = v;
                    else
                        ((u16*)Yv)[(size_t)(rowb + r) * N + col] = f2bf(v);
                }
            }
        }
    }
}

// ---------------------------------------------------------------------------
// Causal attention, 2-pass flash style with SWAPPED QK^T (S^T = K·Q^T).
// Block = (b, h, 64 q-rows); 4 waves x 16 q-rows each.
// Lane (lr,lg) owns q-row q0+lr; scores for kv = kv0+16t+4*lg+r live in
// s[t][r] -> in-lane masking/exp, 2-shfl row reduce, float4 P stores.
// V is pre-transposed: vt[b][h][d][t] -> PV B-frag is one 16B vector load.
// ---------------------------------------------------------------------------
__global__ __launch_bounds__(256) void attn_kernel(
    const u16* __restrict__ qp, const u16* __restrict__ kp,
    const u16* __restrict__ vt, u16* __restrict__ ctx,
    float* __restrict__ attn)
{
    __shared__ u16 plds[4][16][40];   // per-wave P tile [q][kv], stride 40 u16
    const int l = threadIdx.x & 63, w = threadIdx.x >> 6;
    const int lr = l & 15, lg = l >> 4;
    const int b = blockIdx.z, h = blockIdx.y;
    const int q0 = blockIdx.x * 64 + w * 16;

    const size_t bh_off = (size_t)b * T_SEQ * C_DIM + h * HD;
    const u16* qb = qp + bh_off;
    const u16* kb = kp + bh_off;
    const u16* vtb = vt + ((size_t)(b * NH + h) * HD) * T_SEQ;
    float* ab = attn + (size_t)(b * NH + h) * T_SEQ * T_SEQ;

    // scale: 1/sqrt(64) * log2(e)  (exp computed as exp2)
    const float SC = 0.125f * 1.44269504088896f;

    // Q fragments (B-operand: col=q0+lr, k-dim = d)
    const bf16x8 aq0 = *(const bf16x8*)(qb + (size_t)(q0 + lr) * C_DIM + lg * 8);
    const bf16x8 aq1 = *(const bf16x8*)(qb + (size_t)(q0 + lr) * C_DIM + 32 + lg * 8);

    const int qrow = q0 + lr;          // this lane's q row
    const int kv_end = q0 + 16;        // exclusive kv bound for this strip

    float m = -__builtin_inff(), lsum = 0.f;

    // ---- pass 1: row max + sumexp (in exp2 space) ----
    for (int kv0 = 0; kv0 < kv_end; kv0 += 32) {
        f32x4 s[2] = {};
#pragma unroll
        for (int t = 0; t < 2; ++t) {
            const u16* kr = kb + (size_t)(kv0 + t * 16 + lr) * C_DIM;
            bf16x8 k0 = *(const bf16x8*)(kr + lg * 8);
            bf16x8 k1 = *(const bf16x8*)(kr + 32 + lg * 8);
            s[t] = __builtin_amdgcn_mfma_f32_16x16x32_bf16(k0, aq0, s[t], 0, 0, 0);
            s[t] = __builtin_amdgcn_mfma_f32_16x16x32_bf16(k1, aq1, s[t], 0, 0, 0);
        }
        float sv[2][4];
        float mt = -__builtin_inff();
#pragma unroll
        for (int t = 0; t < 2; ++t)
#pragma unroll
            for (int r = 0; r < 4; ++r) {
                float v = s[t][r] * SC;
                if (kv0 + 16 * t + 4 * lg + r > qrow) v = -__builtin_inff();
                sv[t][r] = v;
                mt = fmaxf(mt, v);
            }
        mt = fmaxf(mt, __shfl_xor(mt, 16));
        mt = fmaxf(mt, __shfl_xor(mt, 32));
        const float mn = fmaxf(m, mt);
        float e = 0.f;
#pragma unroll
        for (int t = 0; t < 2; ++t)
#pragma unroll
            for (int r = 0; r < 4; ++r) e += fexp2(sv[t][r] - mn);
        e += __shfl_xor(e, 16);
        e += __shfl_xor(e, 32);
        lsum = lsum * fexp2(m - mn) + e;
        m = mn;
    }

    const float rl = 1.f / lsum;
    f32x4 cacc[4] = {};

    // ---- pass 2: write normalized P, accumulate PV ----
    for (int kv0 = 0; kv0 < T_SEQ; kv0 += 32) {
        if (kv0 >= kv_end) {
            // strictly above diagonal for all 16 rows: exact zeros
            const float4 z = make_float4(0.f, 0.f, 0.f, 0.f);
#pragma unroll
            for (int i = 0; i < 2; ++i) {
                const int idx = i * 64 + l;
                const int row = q0 + (idx >> 3);
                const int c4 = (idx & 7) * 4;
                *(float4*)(ab + (size_t)row * T_SEQ + kv0 + c4) = z;
            }
            continue;
        }
        f32x4 s[2] = {};
#pragma unroll
        for (int t = 0; t < 2; ++t) {
            const u16* kr = kb + (size_t)(kv0 + t * 16 + lr) * C_DIM;
            bf16x8 k0 = *(const bf16x8*)(kr + lg * 8);
            bf16x8 k1 = *(const bf16x8*)(kr + 32 + lg * 8);
            s[t] = __builtin_amdgcn_mfma_f32_16x16x32_bf16(k0, aq0, s[t], 0, 0, 0);
            s[t] = __builtin_amdgcn_mfma_f32_16x16x32_bf16(k1, aq1, s[t], 0, 0, 0);
        }
#pragma unroll
        for (int t = 0; t < 2; ++t) {
            float p[4];
#pragma unroll
            for (int r = 0; r < 4; ++r) {
                float v = s[t][r] * SC;
                if (kv0 + 16 * t + 4 * lg + r > qrow) v = -__builtin_inff();
                p[r] = fexp2(v - m) * rl;
            }
            // normalized P: 16 rows x 64B full-line coalesced
            float4 pv4 = make_float4(p[0], p[1], p[2], p[3]);
            *(float4*)(ab + (size_t)qrow * T_SEQ + kv0 + 16 * t + 4 * lg) = pv4;
            // bf16 copy into per-wave LDS tile [q][kv] for the PV A-frag
            union { u16 h[4]; uint2 q2; } pk;
#pragma unroll
            for (int r = 0; r < 4; ++r) pk.h[r] = f2bf(p[r]);
            *(uint2*)&plds[w][lr][16 * t + 4 * lg] = pk.q2;
        }
        asm volatile("s_waitcnt lgkmcnt(0)" ::: "memory");
        // PV: A = P[16q x 32kv] from LDS, B = V from vt (16B vector loads)
        const bf16x8 pa = *(const bf16x8*)&plds[w][lr][lg * 8];
#pragma unroll
        for (int dt = 0; dt < 4; ++dt) {
            const bf16x8 vf = *(const bf16x8*)(vtb + (size_t)(dt * 16 + lr) * T_SEQ + kv0 + lg * 8);
            cacc[dt] = __builtin_amdgcn_mfma_f32_16x16x32_bf16(pa, vf, cacc[dt], 0, 0, 0);
        }
    }

    u16* cb = ctx + bh_off;
#pragma unroll
    for (int dt = 0; dt < 4; ++dt)
#pragma unroll
        for (int r = 0; r < 4; ++r)
            cb[(size_t)(q0 + lg * 4 + r) * C_DIM + dt * 16 + lr] = f2bf(cacc[dt][r]);
}

// ---------------------------------------------------------------------------
extern "C" void kernel_launch(void* const* d_in, const int* in_sizes, int n_in,
                              void* d_out, int out_size, void* d_ws, size_t ws_size,
                              hipStream_t stream)
{
    const float* q  = (const float*)d_in[0];
    const float* k  = (const float*)d_in[1];
    const float* Wq = (const float*)d_in[2];
    const float* bq = (const float*)d_in[3];
    const float* Wk = (const float*)d_in[4];
    const float* bk = (const float*)d_in[5];
    const float* Wv = (const float*)d_in[6];
    const float* bv = (const float*)d_in[7];
    const float* Wo = (const float*)d_in[8];
    const float* bo = (const float*)d_in[9];
    (void)in_sizes; (void)n_in; (void)out_size; (void)ws_size;

    float* out = (float*)d_out;
    float* attn = out + (size_t)BATCH * T_SEQ * C_DIM;

    const size_t MC = (size_t)BATCH * T_SEQ * C_DIM;   // 4,194,304 elems
    u16* qp  = (u16*)d_ws;
    u16* kp  = qp + MC;
    u16* vt  = kp + MC;          // V^T: [B][H][D][T]
    u16* ctx = vt + MC;
    u16* WqT = ctx + MC;
    u16* WkT = WqT + (size_t)C_DIM * C_DIM;
    u16* WvT = WkT + (size_t)C_DIM * C_DIM;
    u16* WoT = WvT + (size_t)C_DIM * C_DIM;

    transpose_to_bf16<<<dim3(32, 32, 4), dim3(32, 8), 0, stream>>>(
        Wq, Wk, Wv, Wo, WqT, WkT, WvT, WoT);

    const int M = BATCH * T_SEQ;
    dim3 gg(C_DIM / 128, M / 128);
    gemm_bt<true,  0><<<gg, 256, 0, stream>>>(q,  WqT, bq, qp, M, C_DIM, C_DIM);
    gemm_bt<true,  0><<<gg, 256, 0, stream>>>(k,  WkT, bk, kp, M, C_DIM, C_DIM);
    gemm_bt<false, 2><<<gg, 256, 0, stream>>>(kp, WvT, bv, vt, M, C_DIM, C_DIM);

    attn_kernel<<<dim3(T_SEQ / 64, NH, BATCH), 256, 0, stream>>>(qp, kp, vt, ctx, attn);

    gemm_bt<false, 1><<<gg, 256, 0, stream>>>(ctx, WoT, bo, out, M, C_DIM, C_DIM);
}